// Round 10
// baseline (147.562 us; speedup 1.0000x reference)
//
#include <hip/hip_runtime.h>
#include <hip/hip_bf16.h>

#define SS 2048
#define NSPLIT 8

typedef __attribute__((ext_vector_type(8))) short bf16x8;
typedef __attribute__((ext_vector_type(4))) float f32x4;

__device__ __forceinline__ short f2bf(float f){
    unsigned u = __float_as_uint(f);
    u += 0x7fff + ((u >> 16) & 1);   // RNE; inputs finite
    return (short)(u >> 16);
}
__device__ __forceinline__ float bf2f(short s){
    return __uint_as_float(((unsigned)(unsigned short)s) << 16);
}
__device__ __forceinline__ void gload_lds16(const void* g, void* l){
    __builtin_amdgcn_global_load_lds((const __attribute__((address_space(1))) void*)g,
                                     (__attribute__((address_space(3))) void*)l, 16, 0, 0);
}

// ---------------------------------------------------------------------------
// K0: weight prep with coalesced reads + LDS transpose, PLUS fp32->bf16
// pre-conversion of q_in/kv_in.
__global__ __launch_bounds__(256) void k_prep_w(const float* __restrict__ Wq,
                                                const float* __restrict__ Wk,
                                                const float* __restrict__ Wv,
                                                const float* __restrict__ Wo,
                                                const float* __restrict__ q_in,
                                                const float* __restrict__ kv_in,
                                                short* __restrict__ WcatT,
                                                short* __restrict__ WoT,
                                                short* __restrict__ Xb){
    const int bx = blockIdx.x;
    if (bx >= 256) {
        const int b2 = bx - 256;
        const float* src = (b2 < 128) ? q_in : kv_in;
        short* dst = Xb + ((b2 < 128) ? (size_t)0 : (size_t)4194304);
        const int tg = (b2 & 127) * 256 + threadIdx.x;   // 0..32767
        #pragma unroll
        for (int j = 0; j < 8; ++j) {
            size_t off = (size_t)tg * 16 + (size_t)j * 524288;
            float4 f0 = *(const float4*)(src + off);
            float4 f1 = *(const float4*)(src + off + 4);
            float4 f2 = *(const float4*)(src + off + 8);
            float4 f3 = *(const float4*)(src + off + 12);
            short t[16];
            t[0]=f2bf(f0.x); t[1]=f2bf(f0.y); t[2]=f2bf(f0.z); t[3]=f2bf(f0.w);
            t[4]=f2bf(f1.x); t[5]=f2bf(f1.y); t[6]=f2bf(f1.z); t[7]=f2bf(f1.w);
            t[8]=f2bf(f2.x); t[9]=f2bf(f2.y); t[10]=f2bf(f2.z); t[11]=f2bf(f2.w);
            t[12]=f2bf(f3.x); t[13]=f2bf(f3.y); t[14]=f2bf(f3.z); t[15]=f2bf(f3.w);
            *(bf16x8*)(dst + off)     = *(bf16x8*)&t[0];
            *(bf16x8*)(dst + off + 8) = *(bf16x8*)&t[8];
        }
        return;
    }
    __shared__ float Ts[64][65];
    const int r  = threadIdx.x >> 2;
    const int cq = (threadIdx.x & 3) * 16;
    if (bx < 192) {
        const int ktile = bx & 15, ntile = bx >> 4;
        const int k0 = ktile * 64, n0 = ntile * 64;
        if (ntile < 4) {
            const float* base = Wq + (size_t)(k0 + r) * 1024 + ntile * 256;
            #pragma unroll
            for (int i = 0; i < 16; i += 4) {
                float4 a = *(const float4*)(base + cq + i);
                float4 b = *(const float4*)(base + 64 + cq + i);
                float4 c = *(const float4*)(base + 128 + cq + i);
                float4 d = *(const float4*)(base + 192 + cq + i);
                Ts[r][cq+i]   = 0.125f * (a.x + b.x + c.x + d.x);
                Ts[r][cq+i+1] = 0.125f * (a.y + b.y + c.y + d.y);
                Ts[r][cq+i+2] = 0.125f * (a.z + b.z + c.z + d.z);
                Ts[r][cq+i+3] = 0.125f * (a.w + b.w + c.w + d.w);
            }
        } else {
            const float* W = (ntile < 8) ? Wk : Wv;
            const float* base = W + (size_t)(k0 + r) * 256 + (ntile & 3) * 64;
            #pragma unroll
            for (int i = 0; i < 16; i += 4) {
                float4 a = *(const float4*)(base + cq + i);
                Ts[r][cq+i] = a.x; Ts[r][cq+i+1] = a.y;
                Ts[r][cq+i+2] = a.z; Ts[r][cq+i+3] = a.w;
            }
        }
        __syncthreads();
        short tmp[16];
        #pragma unroll
        for (int i = 0; i < 16; ++i) tmp[i] = f2bf(Ts[cq+i][r]);
        short* dst = WcatT + (size_t)(n0 + r) * 1024 + k0 + cq;
        *(bf16x8*)dst       = *(bf16x8*)&tmp[0];
        *(bf16x8*)(dst + 8) = *(bf16x8*)&tmp[8];
    } else {
        const int b2 = bx - 192;
        const int ktile = b2 & 3, ntile = b2 >> 2;
        const int k0 = ktile * 64, n0 = ntile * 64;
        const float* base = Wo + (size_t)(k0 + r) * 1024 + n0;
        #pragma unroll
        for (int i = 0; i < 16; i += 4) {
            float4 a = *(const float4*)(base + cq + i);
            Ts[r][cq+i] = a.x; Ts[r][cq+i+1] = a.y;
            Ts[r][cq+i+2] = a.z; Ts[r][cq+i+3] = a.w;
        }
        __syncthreads();
        short tmp[16];
        #pragma unroll
        for (int i = 0; i < 16; ++i) tmp[i] = f2bf(Ts[cq+i][r]);
        short* dst = WoT + (size_t)(n0 + r) * 256 + k0 + cq;
        *(bf16x8*)dst       = *(bf16x8*)&tmp[0];
        *(bf16x8*)(dst + 8) = *(bf16x8*)&tmp[8];
    }
}

// ---------------------------------------------------------------------------
// K1: fused qkv projection GEMM, 64x64 tile / BK=64, grid (64,12) = 768
// blocks = 3 resident blocks/CU. m97 staging: global_load_lds 16B,
// double-buffered, 1 barrier/step, both-sides XOR swizzle.
__global__ __launch_bounds__(256) void k_gemm1(const short* __restrict__ Xb,
                                               const short* __restrict__ WcatT,
                                               short* __restrict__ pqk,
                                               short* __restrict__ vt){
    const int m0 = blockIdx.x * 64;
    const int n0 = blockIdx.y * 64;
    const short* X = Xb + ((n0 < 256) ? (size_t)0 : (size_t)4194304);
    const int tid = threadIdx.x;
    const int wave = tid >> 6, lane = tid & 63, quad = lane >> 4, l16 = lane & 15;
    const int wrow = (wave & 1) * 32, wcol = (wave >> 1) * 32;

    __shared__ char SMEM[32768];

    f32x4 acc[2][2];
    #pragma unroll
    for (int tm = 0; tm < 2; ++tm)
        #pragma unroll
        for (int tn = 0; tn < 2; ++tn) acc[tm][tn] = f32x4{0.f,0.f,0.f,0.f};

    const int lr8 = lane >> 3;
    const int sb  = ((lane & 7) * 16) ^ (lr8 << 4);
    const char* Abase = (const char*)X     + (size_t)m0 * 2048;
    const char* Bbase = (const char*)WcatT + (size_t)n0 * 2048;

    auto STAGE = [&](int buf, int k0) {
        #pragma unroll
        for (int j = 0; j < 2; ++j) {
            const int row = j * 32 + wave * 8 + lr8;
            const size_t goff = (size_t)row * 2048 + (size_t)k0 * 2 + sb;
            gload_lds16(Abase + goff, SMEM + buf * 16384 + j * 4096 + wave * 1024);
            gload_lds16(Bbase + goff, SMEM + buf * 16384 + 8192 + j * 4096 + wave * 1024);
        }
    };

    STAGE(0, 0);
    for (int k0 = 0; k0 < 1024; k0 += 64) {
        __syncthreads();
        const int cur = (k0 >> 6) & 1;
        if (k0 + 64 < 1024) STAGE(cur ^ 1, k0 + 64);
        #pragma unroll
        for (int ks = 0; ks < 2; ++ks) {
            bf16x8 a[2];
            #pragma unroll
            for (int tm = 0; tm < 2; ++tm) {
                const int R = wrow + tm * 16 + l16;
                const int cswz = ((ks * 64 + quad * 16) ^ ((R & 7) << 4));
                a[tm] = *(const bf16x8*)(SMEM + cur * 16384 + R * 128 + cswz);
            }
            #pragma unroll
            for (int tn = 0; tn < 2; ++tn) {
                const int R2 = wcol + tn * 16 + l16;
                const int cswz2 = ((ks * 64 + quad * 16) ^ ((R2 & 7) << 4));
                bf16x8 b = *(const bf16x8*)(SMEM + cur * 16384 + 8192 + R2 * 128 + cswz2);
                #pragma unroll
                for (int tm = 0; tm < 2; ++tm)
                    acc[tm][tn] = __builtin_amdgcn_mfma_f32_16x16x32_bf16(a[tm], b, acc[tm][tn], 0, 0, 0);
            }
        }
    }
    __syncthreads();

    if (n0 < 512) {
        #pragma unroll
        for (int tm = 0; tm < 2; ++tm) {
            const int mrow = m0 + wrow + tm * 16 + quad * 4;
            #pragma unroll
            for (int tn = 0; tn < 2; ++tn) {
                const int col = n0 + wcol + tn * 16 + l16;
                #pragma unroll
                for (int rg = 0; rg < 4; ++rg)
                    pqk[(size_t)(mrow + rg) * 512 + col] = f2bf(acc[tm][tn][rg]);
            }
        }
    } else {
        short* SM16 = (short*)SMEM;
        #pragma unroll
        for (int tm = 0; tm < 2; ++tm) {
            const int ml = wrow + tm * 16 + quad * 4;
            #pragma unroll
            for (int tn = 0; tn < 2; ++tn) {
                const int cl = wcol + tn * 16 + l16;
                #pragma unroll
                for (int rg = 0; rg < 4; ++rg)
                    SM16[cl * 72 + ml + rg] = f2bf(acc[tm][tn][rg]);
            }
        }
        __syncthreads();
        const int row  = tid >> 2;
        const int part = tid & 3;
        const int colv = (n0 - 512) + row;
        const int vh = colv >> 6, d = colv & 63;
        const int batch = m0 >> 11;
        const int s0 = (m0 & 2047) + part * 16;
        short* dst = vt + ((size_t)((batch * 4 + vh) * 64 + d)) * 2048 + s0;
        const short* src = &SM16[row * 72 + part * 16];
        *(bf16x8*)dst       = *(const bf16x8*)src;
        *(bf16x8*)(dst + 8) = *(const bf16x8*)(src + 8);
    }
}

// ---------------------------------------------------------------------------
// K2: split-K MFMA flash attention, swapped QK^T, NSPLIT=8, cvt_pk P-pack.
__global__ __launch_bounds__(256) void k_attn4(const short* __restrict__ pqk,
                                               const short* __restrict__ vt,
                                               short* __restrict__ Op,
                                               float* __restrict__ Lp){
    const int bx = blockIdx.x;
    const int qt = 31 - (bx / NSPLIT);
    const int s  = bx - (bx / NSPLIT) * NSPLIT;
    const int kv = blockIdx.y, batch = blockIdx.z;
    const int tid = threadIdx.x;
    const int wave = tid >> 6, lane = tid & 63, quad = lane >> 4, l16 = lane & 15;
    const int r = tid >> 2, c = (tid & 3) * 16;
    const int part = (((batch * 4 + kv) * 32 + qt) * NSPLIT + s);

    __shared__ short Ks[64][72];
    __shared__ short Vs[64][72];
    __shared__ short Ps[64][72];

    const size_t qrow = (size_t)(batch * SS + qt * 64 + wave * 16 + l16);
    bf16x8 aq0 = *(const bf16x8*)(pqk + qrow * 512 + kv * 64 + quad * 8);
    bf16x8 aq1 = *(const bf16x8*)(pqk + qrow * 512 + kv * 64 + 32 + quad * 8);

    f32x4 accO[4];
    #pragma unroll
    for (int t = 0; t < 4; ++t) accO[t] = f32x4{0.f, 0.f, 0.f, 0.f};
    float lsum = 0.f;

    bf16x8 rk0, rk1, rv0, rv1;
    int kt = s;
    if (kt <= qt) {
        const short* ksrc = pqk + (size_t)(batch * SS + kt * 64 + r) * 512 + 256 + kv * 64 + c;
        rk0 = *(const bf16x8*)ksrc; rk1 = *(const bf16x8*)(ksrc + 8);
        const short* vsrc = vt + ((size_t)((batch * 4 + kv) * 64 + r)) * 2048 + kt * 64 + c;
        rv0 = *(const bf16x8*)vsrc; rv1 = *(const bf16x8*)(vsrc + 8);
    }
    for (; kt <= qt; kt += NSPLIT) {
        *(bf16x8*)&Ks[r][c]     = rk0;
        *(bf16x8*)&Ks[r][c + 8] = rk1;
        *(bf16x8*)&Vs[r][c]     = rv0;
        *(bf16x8*)&Vs[r][c + 8] = rv1;
        __syncthreads();
        if (kt + NSPLIT <= qt) {
            const short* ksrc = pqk + (size_t)(batch * SS + (kt + NSPLIT) * 64 + r) * 512 + 256 + kv * 64 + c;
            rk0 = *(const bf16x8*)ksrc; rk1 = *(const bf16x8*)(ksrc + 8);
            const short* vsrc = vt + ((size_t)((batch * 4 + kv) * 64 + r)) * 2048 + (kt + NSPLIT) * 64 + c;
            rv0 = *(const bf16x8*)vsrc; rv1 = *(const bf16x8*)(vsrc + 8);
        }

        f32x4 sc[4];
        #pragma unroll
        for (int t = 0; t < 4; ++t) sc[t] = f32x4{0.f, 0.f, 0.f, 0.f};
        #pragma unroll
        for (int ks = 0; ks < 2; ++ks) {
            bf16x8 q = ks ? aq1 : aq0;
            #pragma unroll
            for (int t = 0; t < 4; ++t) {
                bf16x8 kf = *(bf16x8*)&Ks[t * 16 + l16][ks * 32 + quad * 8];
                sc[t] = __builtin_amdgcn_mfma_f32_16x16x32_bf16(kf, q, sc[t], 0, 0, 0);
            }
        }
        if (kt == qt) {
            #pragma unroll
            for (int t = 0; t < 4; ++t) {
                #pragma unroll
                for (int rg = 0; rg < 4; ++rg)
                    if (t * 16 + quad * 4 + rg > wave * 16 + l16) sc[t][rg] = -1e30f;
            }
        }
        #pragma unroll
        for (int t = 0; t < 4; ++t) {
            float p0 = __expf(sc[t][0]);
            float p1 = __expf(sc[t][1]);
            float p2 = __expf(sc[t][2]);
            float p3 = __expf(sc[t][3]);
            lsum += (p0 + p1) + (p2 + p3);
            unsigned lo, hi;
            asm("v_cvt_pk_bf16_f32 %0, %1, %2" : "=v"(lo) : "v"(p0), "v"(p1));
            asm("v_cvt_pk_bf16_f32 %0, %1, %2" : "=v"(hi) : "v"(p2), "v"(p3));
            unsigned long long w = (unsigned long long)lo | ((unsigned long long)hi << 32);
            *(unsigned long long*)&Ps[wave * 16 + l16][t * 16 + quad * 4] = w;
        }
        #pragma unroll
        for (int ks = 0; ks < 2; ++ks) {
            bf16x8 ap = *(bf16x8*)&Ps[wave * 16 + l16][ks * 32 + quad * 8];
            #pragma unroll
            for (int t = 0; t < 4; ++t) {
                bf16x8 bv = *(bf16x8*)&Vs[t * 16 + l16][ks * 32 + quad * 8];
                accO[t] = __builtin_amdgcn_mfma_f32_16x16x32_bf16(ap, bv, accO[t], 0, 0, 0);
            }
        }
        __syncthreads();
    }
    lsum += __shfl_xor(lsum, 16);
    lsum += __shfl_xor(lsum, 32);
    #pragma unroll
    for (int rg = 0; rg < 4; ++rg) {
        int row = wave * 16 + quad * 4 + rg;
        #pragma unroll
        for (int t = 0; t < 4; ++t)
            Op[(size_t)part * 4096 + row * 64 + t * 16 + l16] = f2bf(accO[t][rg]);
    }
    if (quad == 0)
        Lp[part * 64 + wave * 16 + l16] = lsum;
}

// ---------------------------------------------------------------------------
// K3: output projection GEMM with FUSED combine: A-tile is built on the fly
// from the 8 Op partials (fp32 sum in combine's exact i=0..7 order) scaled by
// invL (block-prologue Lp reduction, LDS-cached). Deletes k_combine + its
// launch gap + the ao round-trip. 128x128 tile, fp32 out.
__global__ __launch_bounds__(256) void k_gemm2(const short* __restrict__ Op,
                                               const float* __restrict__ Lp,
                                               const short* __restrict__ WoT,
                                               float* __restrict__ out){
    const int m0 = blockIdx.x * 128;
    const int n0 = blockIdx.y * 128;
    const int tid = threadIdx.x;
    const int wave = tid >> 6, lane = tid & 63, quad = lane >> 4, l16 = lane & 15;
    const int wrow = (wave & 1) * 64, wcol = (wave >> 1) * 64;
    const int r = tid >> 2, cc = (tid & 3) * 16;
    const int batch = m0 >> 11;
    const int qt0 = (m0 & 2047) >> 6;     // rows m0..m0+63 -> qt0, +64.. -> qt0+1

    __shared__ short As[128][72];
    __shared__ short Bs[128][72];
    __shared__ float invLs[512];          // [kv][row0..127]

    // prologue: invLs[kv*128+r0] = 1 / sum_s Lp[part(kv,qt(r0),s)*64 + rin]
    #pragma unroll
    for (int h = 0; h < 2; ++h) {
        const int v = tid + h * 256;
        const int kvv = v >> 7, r0 = v & 127;
        const int qt = qt0 + (r0 >> 6), rin = r0 & 63;
        const int pb = ((batch * 4 + kvv) * 32 + qt) * NSPLIT;
        float ls = 0.f;
        #pragma unroll
        for (int i = 0; i < NSPLIT; ++i) ls += Lp[(pb + i) * 64 + rin];
        invLs[v] = 1.f / ls;
    }

    f32x4 acc[4][4];
    #pragma unroll
    for (int tm = 0; tm < 4; ++tm)
        #pragma unroll
        for (int tn = 0; tn < 4; ++tn) acc[tm][tn] = f32x4{0.f,0.f,0.f,0.f};

    __syncthreads();                      // invLs ready

    for (int k0 = 0; k0 < 256; k0 += 64) {
        const int kv = k0 >> 6;
        const int pbA = ((batch * 4 + kv) * 32 + qt0) * NSPLIT;   // rows m0+r
        const int pbB = pbA + NSPLIT;                              // rows m0+64+r
        // fused combine for A-tile chunk [r][cc..cc+16) and [r+64][cc..cc+16)
        float o0[16], o1[16];
        #pragma unroll
        for (int j = 0; j < 16; ++j) { o0[j] = 0.f; o1[j] = 0.f; }
        #pragma unroll
        for (int i = 0; i < NSPLIT; ++i) {
            const short* sA = Op + (size_t)(pbA + i) * 4096 + r * 64 + cc;
            bf16x8 a0 = *(const bf16x8*)sA;
            bf16x8 a1 = *(const bf16x8*)(sA + 8);
            const short* sB = Op + (size_t)(pbB + i) * 4096 + r * 64 + cc;
            bf16x8 b0 = *(const bf16x8*)sB;
            bf16x8 b1 = *(const bf16x8*)(sB + 8);
            #pragma unroll
            for (int j = 0; j < 8; ++j) {
                o0[j] += bf2f(a0[j]); o0[j + 8] += bf2f(a1[j]);
                o1[j] += bf2f(b0[j]); o1[j + 8] += bf2f(b1[j]);
            }
        }
        const float i0 = invLs[kv * 128 + r];
        const float i1 = invLs[kv * 128 + 64 + r];
        short t0[16], t1[16];
        #pragma unroll
        for (int j = 0; j < 16; ++j) {
            t0[j] = f2bf(o0[j] * i0);
            t1[j] = f2bf(o1[j] * i1);
        }
        *(bf16x8*)&As[r][cc]          = *(bf16x8*)&t0[0];
        *(bf16x8*)&As[r][cc + 8]      = *(bf16x8*)&t0[8];
        *(bf16x8*)&As[r + 64][cc]     = *(bf16x8*)&t1[0];
        *(bf16x8*)&As[r + 64][cc + 8] = *(bf16x8*)&t1[8];
        // B staging (WoT L2-hot, direct loads)
        {
            const short* b0 = WoT + (size_t)(n0 + r) * 256 + k0 + cc;
            const short* b1 = b0 + (size_t)64 * 256;
            *(bf16x8*)&Bs[r][cc]          = *(const bf16x8*)b0;
            *(bf16x8*)&Bs[r][cc + 8]      = *(const bf16x8*)(b0 + 8);
            *(bf16x8*)&Bs[r + 64][cc]     = *(const bf16x8*)b1;
            *(bf16x8*)&Bs[r + 64][cc + 8] = *(const bf16x8*)(b1 + 8);
        }
        __syncthreads();
        #pragma unroll
        for (int ks = 0; ks < 2; ++ks) {
            bf16x8 a[4];
            #pragma unroll
            for (int tm = 0; tm < 4; ++tm)
                a[tm] = *(bf16x8*)&As[wrow + tm * 16 + l16][ks * 32 + quad * 8];
            #pragma unroll
            for (int tn = 0; tn < 4; ++tn) {
                bf16x8 b = *(bf16x8*)&Bs[wcol + tn * 16 + l16][ks * 32 + quad * 8];
                #pragma unroll
                for (int tm = 0; tm < 4; ++tm)
                    acc[tm][tn] = __builtin_amdgcn_mfma_f32_16x16x32_bf16(a[tm], b, acc[tm][tn], 0, 0, 0);
            }
        }
        __syncthreads();
    }
    #pragma unroll
    for (int tm = 0; tm < 4; ++tm) {
        const int mrow = m0 + wrow + tm * 16 + quad * 4;
        #pragma unroll
        for (int tn = 0; tn < 4; ++tn) {
            const int col = n0 + wcol + tn * 16 + l16;
            #pragma unroll
            for (int rg = 0; rg < 4; ++rg)
                out[(size_t)(mrow + rg) * 1024 + col] = acc[tm][tn][rg];
        }
    }
}

extern "C" void kernel_launch(void* const* d_in, const int* in_sizes, int n_in,
                              void* d_out, int out_size, void* d_ws, size_t ws_size,
                              hipStream_t stream) {
    const float* q_in  = (const float*)d_in[0];
    const float* kv_in = (const float*)d_in[1];
    int wqi = 3;
    for (int i = 2; i < n_in; ++i)
        if (in_sizes[i] == 1024 * 16 * 64) { wqi = i; break; }
    const float* Wq = (const float*)d_in[wqi];
    const float* Wk = (const float*)d_in[wqi + 1];
    const float* Wv = (const float*)d_in[wqi + 2];
    const float* Wo = (const float*)d_in[wqi + 3];
    float* out = (float*)d_out;

    char* ws = (char*)d_ws;
    short* WcatT = (short*)(ws);                  // [0, 1.5M)
    short* WoT   = (short*)(ws + 1572864);        // [1.5M, 2M)
    short* pqk   = (short*)(ws + 4194304);        // [4M, 8M)
    short* vt    = (short*)(ws + 8388608);        // [8M, 10M)
    float* Lp    = (float*)(ws + 10485760);       // [10M, +512K)
    short* Op    = (short*)(ws + 33554432);       // [32M, 48M)
    short* Xb    = (short*)(ws + 50331648);       // [48M, 64M)

    hipLaunchKernelGGL(k_prep_w,  dim3(512),     dim3(256), 0, stream,
                       Wq, Wk, Wv, Wo, q_in, kv_in, WcatT, WoT, Xb);
    hipLaunchKernelGGL(k_gemm1,   dim3(64, 12),  dim3(256), 0, stream,
                       Xb, WcatT, pqk, vt);
    hipLaunchKernelGGL(k_attn4,   dim3(32 * NSPLIT, 4, 2), dim3(256), 0, stream,
                       pqk, vt, Op, Lp);
    hipLaunchKernelGGL(k_gemm2,   dim3(32, 8),   dim3(256), 0, stream,
                       Op, Lp, WoT, out);
}

// Round 12
// 139.038 us; speedup vs baseline: 1.0613x; 1.0613x over previous
//
#include <hip/hip_runtime.h>
#include <hip/hip_bf16.h>

#define SS 2048
#define NSPLIT 8

typedef __attribute__((ext_vector_type(8))) short bf16x8;
typedef __attribute__((ext_vector_type(4))) float f32x4;

__device__ __forceinline__ short f2bf(float f){
    unsigned u = __float_as_uint(f);
    u += 0x7fff + ((u >> 16) & 1);   // RNE; inputs finite
    return (short)(u >> 16);
}
__device__ __forceinline__ float bf2f(short s){
    return __uint_as_float(((unsigned)(unsigned short)s) << 16);
}
__device__ __forceinline__ void gload_lds16(const void* g, void* l){
    __builtin_amdgcn_global_load_lds((const __attribute__((address_space(1))) void*)g,
                                     (__attribute__((address_space(3))) void*)l, 16, 0, 0);
}

// ---------------------------------------------------------------------------
// K0: weight prep with coalesced reads + LDS transpose, PLUS fp32->bf16
// pre-conversion of q_in/kv_in.
__global__ __launch_bounds__(256) void k_prep_w(const float* __restrict__ Wq,
                                                const float* __restrict__ Wk,
                                                const float* __restrict__ Wv,
                                                const float* __restrict__ Wo,
                                                const float* __restrict__ q_in,
                                                const float* __restrict__ kv_in,
                                                short* __restrict__ WcatT,
                                                short* __restrict__ WoT,
                                                short* __restrict__ Xb){
    const int bx = blockIdx.x;
    if (bx >= 256) {
        const int b2 = bx - 256;
        const float* src = (b2 < 128) ? q_in : kv_in;
        short* dst = Xb + ((b2 < 128) ? (size_t)0 : (size_t)4194304);
        const int tg = (b2 & 127) * 256 + threadIdx.x;   // 0..32767
        #pragma unroll
        for (int j = 0; j < 8; ++j) {
            size_t off = (size_t)tg * 16 + (size_t)j * 524288;
            float4 f0 = *(const float4*)(src + off);
            float4 f1 = *(const float4*)(src + off + 4);
            float4 f2 = *(const float4*)(src + off + 8);
            float4 f3 = *(const float4*)(src + off + 12);
            short t[16];
            t[0]=f2bf(f0.x); t[1]=f2bf(f0.y); t[2]=f2bf(f0.z); t[3]=f2bf(f0.w);
            t[4]=f2bf(f1.x); t[5]=f2bf(f1.y); t[6]=f2bf(f1.z); t[7]=f2bf(f1.w);
            t[8]=f2bf(f2.x); t[9]=f2bf(f2.y); t[10]=f2bf(f2.z); t[11]=f2bf(f2.w);
            t[12]=f2bf(f3.x); t[13]=f2bf(f3.y); t[14]=f2bf(f3.z); t[15]=f2bf(f3.w);
            *(bf16x8*)(dst + off)     = *(bf16x8*)&t[0];
            *(bf16x8*)(dst + off + 8) = *(bf16x8*)&t[8];
        }
        return;
    }
    __shared__ float Ts[64][65];
    const int r  = threadIdx.x >> 2;
    const int cq = (threadIdx.x & 3) * 16;
    if (bx < 192) {
        const int ktile = bx & 15, ntile = bx >> 4;
        const int k0 = ktile * 64, n0 = ntile * 64;
        if (ntile < 4) {
            const float* base = Wq + (size_t)(k0 + r) * 1024 + ntile * 256;
            #pragma unroll
            for (int i = 0; i < 16; i += 4) {
                float4 a = *(const float4*)(base + cq + i);
                float4 b = *(const float4*)(base + 64 + cq + i);
                float4 c = *(const float4*)(base + 128 + cq + i);
                float4 d = *(const float4*)(base + 192 + cq + i);
                Ts[r][cq+i]   = 0.125f * (a.x + b.x + c.x + d.x);
                Ts[r][cq+i+1] = 0.125f * (a.y + b.y + c.y + d.y);
                Ts[r][cq+i+2] = 0.125f * (a.z + b.z + c.z + d.z);
                Ts[r][cq+i+3] = 0.125f * (a.w + b.w + c.w + d.w);
            }
        } else {
            const float* W = (ntile < 8) ? Wk : Wv;
            const float* base = W + (size_t)(k0 + r) * 256 + (ntile & 3) * 64;
            #pragma unroll
            for (int i = 0; i < 16; i += 4) {
                float4 a = *(const float4*)(base + cq + i);
                Ts[r][cq+i] = a.x; Ts[r][cq+i+1] = a.y;
                Ts[r][cq+i+2] = a.z; Ts[r][cq+i+3] = a.w;
            }
        }
        __syncthreads();
        short tmp[16];
        #pragma unroll
        for (int i = 0; i < 16; ++i) tmp[i] = f2bf(Ts[cq+i][r]);
        short* dst = WcatT + (size_t)(n0 + r) * 1024 + k0 + cq;
        *(bf16x8*)dst       = *(bf16x8*)&tmp[0];
        *(bf16x8*)(dst + 8) = *(bf16x8*)&tmp[8];
    } else {
        const int b2 = bx - 192;
        const int ktile = b2 & 3, ntile = b2 >> 2;
        const int k0 = ktile * 64, n0 = ntile * 64;
        const float* base = Wo + (size_t)(k0 + r) * 1024 + n0;
        #pragma unroll
        for (int i = 0; i < 16; i += 4) {
            float4 a = *(const float4*)(base + cq + i);
            Ts[r][cq+i] = a.x; Ts[r][cq+i+1] = a.y;
            Ts[r][cq+i+2] = a.z; Ts[r][cq+i+3] = a.w;
        }
        __syncthreads();
        short tmp[16];
        #pragma unroll
        for (int i = 0; i < 16; ++i) tmp[i] = f2bf(Ts[cq+i][r]);
        short* dst = WoT + (size_t)(n0 + r) * 256 + k0 + cq;
        *(bf16x8*)dst       = *(bf16x8*)&tmp[0];
        *(bf16x8*)(dst + 8) = *(bf16x8*)&tmp[8];
    }
}

// ---------------------------------------------------------------------------
// K1: fused qkv projection GEMM, 64x64 tile / BK=64, grid (64,12) = 768
// blocks = 3 resident blocks/CU. m97 staging: global_load_lds 16B,
// double-buffered, 1 barrier/step, both-sides XOR swizzle.
__global__ __launch_bounds__(256) void k_gemm1(const short* __restrict__ Xb,
                                               const short* __restrict__ WcatT,
                                               short* __restrict__ pqk,
                                               short* __restrict__ vt){
    const int m0 = blockIdx.x * 64;
    const int n0 = blockIdx.y * 64;
    const short* X = Xb + ((n0 < 256) ? (size_t)0 : (size_t)4194304);
    const int tid = threadIdx.x;
    const int wave = tid >> 6, lane = tid & 63, quad = lane >> 4, l16 = lane & 15;
    const int wrow = (wave & 1) * 32, wcol = (wave >> 1) * 32;

    __shared__ char SMEM[32768];

    f32x4 acc[2][2];
    #pragma unroll
    for (int tm = 0; tm < 2; ++tm)
        #pragma unroll
        for (int tn = 0; tn < 2; ++tn) acc[tm][tn] = f32x4{0.f,0.f,0.f,0.f};

    const int lr8 = lane >> 3;
    const int sb  = ((lane & 7) * 16) ^ (lr8 << 4);
    const char* Abase = (const char*)X     + (size_t)m0 * 2048;
    const char* Bbase = (const char*)WcatT + (size_t)n0 * 2048;

    auto STAGE = [&](int buf, int k0) {
        #pragma unroll
        for (int j = 0; j < 2; ++j) {
            const int row = j * 32 + wave * 8 + lr8;
            const size_t goff = (size_t)row * 2048 + (size_t)k0 * 2 + sb;
            gload_lds16(Abase + goff, SMEM + buf * 16384 + j * 4096 + wave * 1024);
            gload_lds16(Bbase + goff, SMEM + buf * 16384 + 8192 + j * 4096 + wave * 1024);
        }
    };

    STAGE(0, 0);
    for (int k0 = 0; k0 < 1024; k0 += 64) {
        __syncthreads();
        const int cur = (k0 >> 6) & 1;
        if (k0 + 64 < 1024) STAGE(cur ^ 1, k0 + 64);
        #pragma unroll
        for (int ks = 0; ks < 2; ++ks) {
            bf16x8 a[2];
            #pragma unroll
            for (int tm = 0; tm < 2; ++tm) {
                const int R = wrow + tm * 16 + l16;
                const int cswz = ((ks * 64 + quad * 16) ^ ((R & 7) << 4));
                a[tm] = *(const bf16x8*)(SMEM + cur * 16384 + R * 128 + cswz);
            }
            #pragma unroll
            for (int tn = 0; tn < 2; ++tn) {
                const int R2 = wcol + tn * 16 + l16;
                const int cswz2 = ((ks * 64 + quad * 16) ^ ((R2 & 7) << 4));
                bf16x8 b = *(const bf16x8*)(SMEM + cur * 16384 + 8192 + R2 * 128 + cswz2);
                #pragma unroll
                for (int tm = 0; tm < 2; ++tm)
                    acc[tm][tn] = __builtin_amdgcn_mfma_f32_16x16x32_bf16(a[tm], b, acc[tm][tn], 0, 0, 0);
            }
        }
    }
    __syncthreads();

    if (n0 < 512) {
        #pragma unroll
        for (int tm = 0; tm < 2; ++tm) {
            const int mrow = m0 + wrow + tm * 16 + quad * 4;
            #pragma unroll
            for (int tn = 0; tn < 2; ++tn) {
                const int col = n0 + wcol + tn * 16 + l16;
                #pragma unroll
                for (int rg = 0; rg < 4; ++rg)
                    pqk[(size_t)(mrow + rg) * 512 + col] = f2bf(acc[tm][tn][rg]);
            }
        }
    } else {
        short* SM16 = (short*)SMEM;
        #pragma unroll
        for (int tm = 0; tm < 2; ++tm) {
            const int ml = wrow + tm * 16 + quad * 4;
            #pragma unroll
            for (int tn = 0; tn < 2; ++tn) {
                const int cl = wcol + tn * 16 + l16;
                #pragma unroll
                for (int rg = 0; rg < 4; ++rg)
                    SM16[cl * 72 + ml + rg] = f2bf(acc[tm][tn][rg]);
            }
        }
        __syncthreads();
        const int row  = tid >> 2;
        const int part = tid & 3;
        const int colv = (n0 - 512) + row;
        const int vh = colv >> 6, d = colv & 63;
        const int batch = m0 >> 11;
        const int s0 = (m0 & 2047) + part * 16;
        short* dst = vt + ((size_t)((batch * 4 + vh) * 64 + d)) * 2048 + s0;
        const short* src = &SM16[row * 72 + part * 16];
        *(bf16x8*)dst       = *(const bf16x8*)src;
        *(bf16x8*)(dst + 8) = *(const bf16x8*)(src + 8);
    }
}

// ---------------------------------------------------------------------------
// K2: split-K MFMA flash attention, swapped QK^T, NSPLIT=8, cvt_pk P-pack.
__global__ __launch_bounds__(256) void k_attn4(const short* __restrict__ pqk,
                                               const short* __restrict__ vt,
                                               short* __restrict__ Op,
                                               float* __restrict__ Lp){
    const int bx = blockIdx.x;
    const int qt = 31 - (bx / NSPLIT);
    const int s  = bx - (bx / NSPLIT) * NSPLIT;
    const int kv = blockIdx.y, batch = blockIdx.z;
    const int tid = threadIdx.x;
    const int wave = tid >> 6, lane = tid & 63, quad = lane >> 4, l16 = lane & 15;
    const int r = tid >> 2, c = (tid & 3) * 16;
    const int part = (((batch * 4 + kv) * 32 + qt) * NSPLIT + s);

    __shared__ short Ks[64][72];
    __shared__ short Vs[64][72];
    __shared__ short Ps[64][72];

    const size_t qrow = (size_t)(batch * SS + qt * 64 + wave * 16 + l16);
    bf16x8 aq0 = *(const bf16x8*)(pqk + qrow * 512 + kv * 64 + quad * 8);
    bf16x8 aq1 = *(const bf16x8*)(pqk + qrow * 512 + kv * 64 + 32 + quad * 8);

    f32x4 accO[4];
    #pragma unroll
    for (int t = 0; t < 4; ++t) accO[t] = f32x4{0.f, 0.f, 0.f, 0.f};
    float lsum = 0.f;

    bf16x8 rk0, rk1, rv0, rv1;
    int kt = s;
    if (kt <= qt) {
        const short* ksrc = pqk + (size_t)(batch * SS + kt * 64 + r) * 512 + 256 + kv * 64 + c;
        rk0 = *(const bf16x8*)ksrc; rk1 = *(const bf16x8*)(ksrc + 8);
        const short* vsrc = vt + ((size_t)((batch * 4 + kv) * 64 + r)) * 2048 + kt * 64 + c;
        rv0 = *(const bf16x8*)vsrc; rv1 = *(const bf16x8*)(vsrc + 8);
    }
    for (; kt <= qt; kt += NSPLIT) {
        *(bf16x8*)&Ks[r][c]     = rk0;
        *(bf16x8*)&Ks[r][c + 8] = rk1;
        *(bf16x8*)&Vs[r][c]     = rv0;
        *(bf16x8*)&Vs[r][c + 8] = rv1;
        __syncthreads();
        if (kt + NSPLIT <= qt) {
            const short* ksrc = pqk + (size_t)(batch * SS + (kt + NSPLIT) * 64 + r) * 512 + 256 + kv * 64 + c;
            rk0 = *(const bf16x8*)ksrc; rk1 = *(const bf16x8*)(ksrc + 8);
            const short* vsrc = vt + ((size_t)((batch * 4 + kv) * 64 + r)) * 2048 + (kt + NSPLIT) * 64 + c;
            rv0 = *(const bf16x8*)vsrc; rv1 = *(const bf16x8*)(vsrc + 8);
        }

        f32x4 sc[4];
        #pragma unroll
        for (int t = 0; t < 4; ++t) sc[t] = f32x4{0.f, 0.f, 0.f, 0.f};
        #pragma unroll
        for (int ks = 0; ks < 2; ++ks) {
            bf16x8 q = ks ? aq1 : aq0;
            #pragma unroll
            for (int t = 0; t < 4; ++t) {
                bf16x8 kf = *(bf16x8*)&Ks[t * 16 + l16][ks * 32 + quad * 8];
                sc[t] = __builtin_amdgcn_mfma_f32_16x16x32_bf16(kf, q, sc[t], 0, 0, 0);
            }
        }
        if (kt == qt) {
            #pragma unroll
            for (int t = 0; t < 4; ++t) {
                #pragma unroll
                for (int rg = 0; rg < 4; ++rg)
                    if (t * 16 + quad * 4 + rg > wave * 16 + l16) sc[t][rg] = -1e30f;
            }
        }
        #pragma unroll
        for (int t = 0; t < 4; ++t) {
            float p0 = __expf(sc[t][0]);
            float p1 = __expf(sc[t][1]);
            float p2 = __expf(sc[t][2]);
            float p3 = __expf(sc[t][3]);
            lsum += (p0 + p1) + (p2 + p3);
            unsigned lo, hi;
            asm("v_cvt_pk_bf16_f32 %0, %1, %2" : "=v"(lo) : "v"(p0), "v"(p1));
            asm("v_cvt_pk_bf16_f32 %0, %1, %2" : "=v"(hi) : "v"(p2), "v"(p3));
            unsigned long long w = (unsigned long long)lo | ((unsigned long long)hi << 32);
            *(unsigned long long*)&Ps[wave * 16 + l16][t * 16 + quad * 4] = w;
        }
        #pragma unroll
        for (int ks = 0; ks < 2; ++ks) {
            bf16x8 ap = *(bf16x8*)&Ps[wave * 16 + l16][ks * 32 + quad * 8];
            #pragma unroll
            for (int t = 0; t < 4; ++t) {
                bf16x8 bv = *(bf16x8*)&Vs[t * 16 + l16][ks * 32 + quad * 8];
                accO[t] = __builtin_amdgcn_mfma_f32_16x16x32_bf16(ap, bv, accO[t], 0, 0, 0);
            }
        }
        __syncthreads();
    }
    lsum += __shfl_xor(lsum, 16);
    lsum += __shfl_xor(lsum, 32);
    #pragma unroll
    for (int rg = 0; rg < 4; ++rg) {
        int row = wave * 16 + quad * 4 + rg;
        #pragma unroll
        for (int t = 0; t < 4; ++t)
            Op[(size_t)part * 4096 + row * 64 + t * 16 + l16] = f2bf(accO[t][rg]);
    }
    if (quad == 0)
        Lp[part * 64 + wave * 16 + l16] = lsum;
}

// K2b: linear merge of NSPLIT bf16 partials -> ao bf16 [4096][256]
__global__ __launch_bounds__(256) void k_combine(const short* __restrict__ Op,
                                                 const float* __restrict__ Lp,
                                                 short* __restrict__ ao){
    const int qt = blockIdx.x, kv = blockIdx.y, batch = blockIdx.z;
    const int tid = threadIdx.x;
    const int rr = tid >> 2, cs = (tid & 3) * 16;
    const int pbase = ((batch * 4 + kv) * 32 + qt) * NSPLIT;
    float lsum = 0.f;
    #pragma unroll
    for (int i = 0; i < NSPLIT; ++i) lsum += Lp[(pbase + i) * 64 + rr];
    float inv = 1.f / lsum;
    float o[16];
    #pragma unroll
    for (int j = 0; j < 16; ++j) o[j] = 0.f;
    #pragma unroll
    for (int i = 0; i < NSPLIT; ++i) {
        const short* src = Op + (size_t)(pbase + i) * 4096 + rr * 64 + cs;
        bf16x8 v0 = *(const bf16x8*)src;
        bf16x8 v1 = *(const bf16x8*)(src + 8);
        #pragma unroll
        for (int j = 0; j < 8; ++j) { o[j] += bf2f(v0[j]); o[j + 8] += bf2f(v1[j]); }
    }
    short* dst = ao + (size_t)(batch * SS + qt * 64 + rr) * 256 + kv * 64 + cs;
    #pragma unroll
    for (int j = 0; j < 16; ++j)
        dst[j] = f2bf(o[j] * inv);
}

// ---------------------------------------------------------------------------
// K3: output projection GEMM, 128x128 tile, register-prefetched. fp32 out.
__global__ __launch_bounds__(256) void k_gemm2(const short* __restrict__ ao,
                                               const short* __restrict__ WoT,
                                               float* __restrict__ out){
    const int m0 = blockIdx.x * 128;
    const int n0 = blockIdx.y * 128;
    const int tid = threadIdx.x;
    const int wave = tid >> 6, lane = tid & 63, quad = lane >> 4, l16 = lane & 15;
    const int wrow = (wave & 1) * 64, wcol = (wave >> 1) * 64;
    const int r = tid >> 2, cc = (tid & 3) * 16;

    __shared__ short As[128][72];
    __shared__ short Bs[128][72];

    f32x4 acc[4][4];
    #pragma unroll
    for (int tm = 0; tm < 4; ++tm)
        #pragma unroll
        for (int tn = 0; tn < 4; ++tn) acc[tm][tn] = f32x4{0.f,0.f,0.f,0.f};

    bf16x8 ra0, ra1, ra2, ra3, rb0, rb1, rb2, rb3;
    {
        const short* a0 = ao + (size_t)(m0 + r) * 256 + cc;
        const short* a1 = a0 + (size_t)64 * 256;
        const short* b0 = WoT + (size_t)(n0 + r) * 256 + cc;
        const short* b1 = b0 + (size_t)64 * 256;
        ra0 = *(const bf16x8*)a0; ra1 = *(const bf16x8*)(a0 + 8);
        ra2 = *(const bf16x8*)a1; ra3 = *(const bf16x8*)(a1 + 8);
        rb0 = *(const bf16x8*)b0; rb1 = *(const bf16x8*)(b0 + 8);
        rb2 = *(const bf16x8*)b1; rb3 = *(const bf16x8*)(b1 + 8);
    }
    for (int k0 = 0; k0 < 256; k0 += 64) {
        *(bf16x8*)&As[r][cc]          = ra0;
        *(bf16x8*)&As[r][cc + 8]      = ra1;
        *(bf16x8*)&As[r + 64][cc]     = ra2;
        *(bf16x8*)&As[r + 64][cc + 8] = ra3;
        *(bf16x8*)&Bs[r][cc]          = rb0;
        *(bf16x8*)&Bs[r][cc + 8]      = rb1;
        *(bf16x8*)&Bs[r + 64][cc]     = rb2;
        *(bf16x8*)&Bs[r + 64][cc + 8] = rb3;
        __syncthreads();
        if (k0 + 64 < 256) {
            const short* a0 = ao + (size_t)(m0 + r) * 256 + k0 + 64 + cc;
            const short* a1 = a0 + (size_t)64 * 256;
            const short* b0 = WoT + (size_t)(n0 + r) * 256 + k0 + 64 + cc;
            const short* b1 = b0 + (size_t)64 * 256;
            ra0 = *(const bf16x8*)a0; ra1 = *(const bf16x8*)(a0 + 8);
            ra2 = *(const bf16x8*)a1; ra3 = *(const bf16x8*)(a1 + 8);
            rb0 = *(const bf16x8*)b0; rb1 = *(const bf16x8*)(b0 + 8);
            rb2 = *(const bf16x8*)b1; rb3 = *(const bf16x8*)(b1 + 8);
        }
        #pragma unroll
        for (int ks = 0; ks < 2; ++ks) {
            bf16x8 a[4];
            #pragma unroll
            for (int tm = 0; tm < 4; ++tm)
                a[tm] = *(bf16x8*)&As[wrow + tm * 16 + l16][ks * 32 + quad * 8];
            #pragma unroll
            for (int tn = 0; tn < 4; ++tn) {
                bf16x8 b = *(bf16x8*)&Bs[wcol + tn * 16 + l16][ks * 32 + quad * 8];
                #pragma unroll
                for (int tm = 0; tm < 4; ++tm)
                    acc[tm][tn] = __builtin_amdgcn_mfma_f32_16x16x32_bf16(a[tm], b, acc[tm][tn], 0, 0, 0);
            }
        }
        __syncthreads();
    }
    #pragma unroll
    for (int tm = 0; tm < 4; ++tm) {
        const int mrow = m0 + wrow + tm * 16 + quad * 4;
        #pragma unroll
        for (int tn = 0; tn < 4; ++tn) {
            const int col = n0 + wcol + tn * 16 + l16;
            #pragma unroll
            for (int rg = 0; rg < 4; ++rg)
                out[(size_t)(mrow + rg) * 1024 + col] = acc[tm][tn][rg];
        }
    }
}

extern "C" void kernel_launch(void* const* d_in, const int* in_sizes, int n_in,
                              void* d_out, int out_size, void* d_ws, size_t ws_size,
                              hipStream_t stream) {
    const float* q_in  = (const float*)d_in[0];
    const float* kv_in = (const float*)d_in[1];
    int wqi = 3;
    for (int i = 2; i < n_in; ++i)
        if (in_sizes[i] == 1024 * 16 * 64) { wqi = i; break; }
    const float* Wq = (const float*)d_in[wqi];
    const float* Wk = (const float*)d_in[wqi + 1];
    const float* Wv = (const float*)d_in[wqi + 2];
    const float* Wo = (const float*)d_in[wqi + 3];
    float* out = (float*)d_out;

    char* ws = (char*)d_ws;
    short* WcatT = (short*)(ws);                  // [0, 1.5M)
    short* WoT   = (short*)(ws + 1572864);        // [1.5M, 2M)
    short* ao    = (short*)(ws + 2097152);        // [2M, 4M)
    short* pqk   = (short*)(ws + 4194304);        // [4M, 8M)
    short* vt    = (short*)(ws + 8388608);        // [8M, 10M)
    float* Lp    = (float*)(ws + 10485760);       // [10M, +512K)
    short* Op    = (short*)(ws + 33554432);       // [32M, 48M)
    short* Xb    = (short*)(ws + 50331648);       // [48M, 64M)

    hipLaunchKernelGGL(k_prep_w,  dim3(512),     dim3(256), 0, stream,
                       Wq, Wk, Wv, Wo, q_in, kv_in, WcatT, WoT, Xb);
    hipLaunchKernelGGL(k_gemm1,   dim3(64, 12),  dim3(256), 0, stream,
                       Xb, WcatT, pqk, vt);
    hipLaunchKernelGGL(k_attn4,   dim3(32 * NSPLIT, 4, 2), dim3(256), 0, stream,
                       pqk, vt, Op, Lp);
    hipLaunchKernelGGL(k_combine, dim3(32, 4, 2), dim3(256), 0, stream,
                       Op, Lp, ao);
    hipLaunchKernelGGL(k_gemm2,   dim3(32, 8),   dim3(256), 0, stream,
                       ao, WoT, out);
}